// Round 2
// baseline (163.654 us; speedup 1.0000x reference)
//
#include <hip/hip_runtime.h>
#include <math.h>

namespace {
constexpr int WIN_    = 1024;
constexpr int HOP_    = 256;
constexpr int FRAMES_ = 1024;
constexpr int BATCH_  = 16;
constexpr int BINS_   = 513;
constexpr int OUTLEN_ = (FRAMES_ - 1) * HOP_ + WIN_;   // 262912
constexpr int FPB_    = 32;                            // frames owned per block
constexpr int BPB_    = FRAMES_ / FPB_;                // 32 blocks per batch
constexpr int OWN_    = FPB_ * HOP_;                   // 8192 owned samples
constexpr int BUF_    = OWN_ + (WIN_ - HOP_);          // 8960 (last block's span)
}

// One block owns output samples [F0*HOP, F0*HOP + blen). It computes the
// windowed irfft of frames F0-3 .. F0+FPB-1 (3-frame recompute covers the
// left seam), accumulates into an LDS buffer, then writes its span with
// exclusive float4 stores. No workspace, no atomics, fully deterministic.
__global__ __launch_bounds__(256)
void istft_fused_kernel(const float* __restrict__ sre,
                        const float* __restrict__ sim,
                        float* __restrict__ out)
{
    __shared__ __align__(16) float acc[BUF_];
    __shared__ float Ar[512], Ai[512], Br[512], Bi[512];
    __shared__ float Tr[256], Ti[256];

    const int i     = threadIdx.x;       // 0..255
    const int blkid = blockIdx.x;        // 0..BPB-1 within batch
    const int b     = blockIdx.y;        // batch
    const int F0    = blkid * FPB_;
    const int blen  = (blkid == BPB_ - 1) ? BUF_ : OWN_;

    // Twiddle table T[j] = exp(+2*pi*i*j/512), j=0..255
    {
        float s, c;
        sincosf(0.012271846303085130f * (float)i, &s, &c);  // 2*pi/512 * i
        Tr[i] = c; Ti[i] = s;
    }
    // Zero the accumulator
    {
        float4* a4 = reinterpret_cast<float4*>(acc);
        for (int v = i; v < BUF_ / 4; v += 256)
            a4[v] = make_float4(0.f, 0.f, 0.f, 0.f);
    }
    __syncthreads();

    const float C1 = 0.9999811753f;   // cos(2*pi/1024)
    const float S1 = 0.0061358846f;   // sin(2*pi/1024)

    #pragma unroll 1
    for (int fi = -3; fi < FPB_; ++fi) {
        const int f = F0 + fi;
        if (f < 0) continue;          // uniform per block (only blkid==0)
        const size_t base = ((size_t)b * FRAMES_ + f) * BINS_;

        // ---- Z-prep: Z[k] = E[k] + i*O[k], scale 1/1024 folds /2 and 1/512.
        // c2r semantics: imag of bins 0 and 512 ignored.
        #pragma unroll
        for (int h = 0; h < 2; ++h) {
            const int kk = i + h * 256;
            const bool dc = (kk == 0);
            float ar = sre[base + kk];
            float ai = dc ? 0.0f : sim[base + kk];
            float br = sre[base + (512 - kk)];
            float bi = dc ? 0.0f : -sim[base + (512 - kk)];
            const float cs = (1.0f / 1024.0f);
            float er = (ar + br) * cs, ei = (ai + bi) * cs;
            float dr = (ar - br) * cs, di = (ai - bi) * cs;
            float wr = Tr[kk >> 1], wi = Ti[kk >> 1];
            if (kk & 1) {   // odd k: rotate by e^{2*pi*i/1024}
                float nr = wr * C1 - wi * S1;
                float ni = wr * S1 + wi * C1;
                wr = nr; wi = ni;
            }
            float o_r = wr * dr - wi * di;
            float o_i = wr * di + wi * dr;
            Ar[kk] = er - o_i;   // Re(E + i*O)
            Ai[kk] = ei + o_r;   // Im(E + i*O)
        }
        __syncthreads();

        // ---- 512-pt Stockham DIF IFFT (sign +), natural order in/out.
        float* xr = Ar; float* xi = Ai; float* yr = Br; float* yi = Bi;
        #pragma unroll
        for (int k = 0; k < 9; ++k) {
            const int smask = (1 << k) - 1;
            const int q = i & smask;
            const int p = i >> k;
            const int j = i & ~smask;          // twiddle idx = p<<k
            float a_r = xr[i],       a_i = xi[i];
            float b_r = xr[i + 256], b_i = xi[i + 256];
            const float wr = Tr[j], wi = Ti[j];
            const int w0 = q + (p << (k + 1));
            const float s_r = a_r - b_r, s_i = a_i - b_i;
            yr[w0] = a_r + b_r;
            yi[w0] = a_i + b_i;
            yr[w0 + (1 << k)] = s_r * wr - s_i * wi;
            yi[w0 + (1 << k)] = s_r * wi + s_i * wr;
            __syncthreads();
            float* t0 = xr; xr = yr; yr = t0;
            float* t1 = xi; xi = yi; yi = t1;
        }
        // z[m] now in xr/xi (Br/Bi): x[2m]=Re z[m], x[2m+1]=Im z[m]

        // ---- window * frame, accumulate into acc (thread-exclusive slots;
        // epilogue(f) races nothing: next frame's LDS writes are behind the
        // z-prep barrier and touch Ar/Ai, we read Br/Bi).
        #pragma unroll
        for (int h = 0; h < 2; ++h) {
            const int m = i + h * 256;
            const float zr = xr[m], zi = xi[m];
            const float sgn = (h == 0) ? 1.0f : -1.0f;
            const float cr = sgn * Tr[i], ci = sgn * Ti[i];
            const float w0 = 0.5f - 0.5f * cr;                 // hann(2m)
            const float w1 = 0.5f - 0.5f * (cr * C1 - ci * S1); // hann(2m+1)
            const int pos = fi * HOP_ + 2 * m;   // even
            if ((unsigned)pos < (unsigned)blen) {
                float2* p2 = reinterpret_cast<float2*>(acc) + (pos >> 1);
                float2 v = *p2;
                v.x += zr * w0;
                v.y += zi * w1;
                *p2 = v;
            }
        }
    }
    __syncthreads();

    // ---- exclusive write-out of the owned span
    const float4* s4 = reinterpret_cast<const float4*>(acc);
    float4* o4 = reinterpret_cast<float4*>(
        out + (size_t)b * OUTLEN_ + (size_t)F0 * HOP_);
    const int nv4 = blen >> 2;
    for (int v = i; v < nv4; v += 256) o4[v] = s4[v];
}

extern "C" void kernel_launch(void* const* d_in, const int* in_sizes, int n_in,
                              void* d_out, int out_size, void* d_ws, size_t ws_size,
                              hipStream_t stream)
{
    (void)in_sizes; (void)n_in; (void)d_ws; (void)ws_size; (void)out_size;
    const float* sre = (const float*)d_in[0];
    const float* sim = (const float*)d_in[1];
    float* out = (float*)d_out;

    istft_fused_kernel<<<dim3(BPB_, BATCH_), dim3(256), 0, stream>>>(sre, sim, out);
}